// Round 5
// baseline (144.396 us; speedup 1.0000x reference)
//
#include <hip/hip_runtime.h>
#include <hip/hip_cooperative_groups.h>
#include <math.h>

namespace cg = cooperative_groups;

#define BATCH_N 884736    // 96*96*96
#define NTOT   1769472    // 2*BATCH_N
#define GBX 128           // blocks per batch
#define NBLK 256          // total blocks = GBX*2 = one per CU (LDS-limited 1/CU)
#define WPB 12            // waves per block
#define THREADS 768
#define GWAVES 1536       // waves per batch = GBX*WPB
#define NCHUNK 9          // chunks per wave: 13824 chunk-slots / 1536
#define MM4 1728          // float4 per block for minmax slice: NTOT/4/NBLK
#define ROWB 80           // tile row stride bytes (64 voxels + 16 pad)
#define TILE_B 5440       // 68*80 bytes per tile (rows -1..66 padded)
#define WAVE_B 10880      // A+B tiles per wave
#define MROW 66           // merge region row stride (floats)
#define QS 190.0f         // weight quantization scale (max w=2/3 -> 127)

// ws layout (bytes):
//   ghist at   256 : float[2][4096]     (zeroed phase A, atomic-accum phase B)
//   kblk  at 36864 : unsigned[256][4]   (plain per-block minmax keys)
#define OFF_GHIST 256
#define OFF_KBLK 36864

typedef int v4i __attribute__((ext_vector_type(4)));

// monotone float->uint key: max over keys == max over floats
__device__ __forceinline__ unsigned fkey(float x){
    unsigned u = __float_as_uint(x);
    return (u & 0x80000000u) ? ~u : (u | 0x80000000u);
}
__device__ __forceinline__ float fdecode(unsigned k){
    return __uint_as_float((k & 0x80000000u) ? (k ^ 0x80000000u) : ~k);
}

// cubic B-spline weights for bins it0-1..it0+2, u = frac(v) in [0,1)
__device__ __forceinline__ void bw4(float u, float w[4]){
    float um = 1.f - u;
    float u2 = u*u, um2 = um*um;
    w[0] = um2*um*(1.f/6.f);
    w[3] = u2*u*(1.f/6.f);
    w[1] = 0.6666666666666667f - u2 + 0.5f*u2*u;
    w[2] = 0.6666666666666667f - um2 + 0.5f*um2*um;
}

__device__ __forceinline__ float bsum(float v, float* red){
    #pragma unroll
    for (int off = 32; off; off >>= 1) v += __shfl_down(v, off);
    int wid = threadIdx.x >> 6, lane = threadIdx.x & 63;
    __syncthreads();              // protect red[] from previous round
    if (lane == 0) red[wid] = v;
    __syncthreads();
    float s = 0.f;
    #pragma unroll
    for (int j = 0; j < WPB; ++j) s += red[j];
    return s;
}

// Fused NMI: phase A per-block minmax -> grid sync -> phase B histogram-GEMM
// (R3-proven i8 MFMA core, wave-private LDS tiles) + ghist atomics -> grid
// sync -> phase C (block 0) entropies + NMI.
__global__ void __launch_bounds__(THREADS, 3)
k_nmi(const float* __restrict__ t, const float* __restrict__ s,
      float* __restrict__ ghist, unsigned* __restrict__ kblk,
      float* __restrict__ out){
    __shared__ int4 smem4[WPB*WAVE_B/16];   // 130560 B: 12 waves * (A+B tiles)
    __shared__ unsigned kred[WPB][4];
    __shared__ float redf[WPB];

    cg::grid_group grid = cg::this_grid();

    int tid = threadIdx.x;
    int lane = tid & 63;
    int warp = tid >> 6;
    int rrow = lane & 15;                  // fragment row/col within 16-tile
    int kgrp = lane >> 4;                  // k-group (16 bytes each for K=64 i8)
    int bx = blockIdx.x, by = blockIdx.y;
    int linear = by*GBX + bx;              // 0..255

    // ---------------- phase A: zero ghist + per-block minmax ----------------
    if (linear < 8){
        for (int i = tid; i < 1024; i += THREADS)
            __hip_atomic_store(&ghist[linear*1024 + i], 0.f,
                               __ATOMIC_RELAXED, __HIP_MEMORY_SCOPE_AGENT);
    }
    {
        const float4* t4 = (const float4*)t;
        const float4* s4 = (const float4*)s;
        unsigned mt=0u, mnt=0u, ms=0u, mns=0u;
        int i0 = linear*MM4;
        for (int i = i0 + tid; i < i0 + MM4; i += THREADS){
            float4 a = t4[i];
            float4 b = s4[i];
            mt  = max(mt,  max(max(fkey(a.x),  fkey(a.y)),  max(fkey(a.z),  fkey(a.w))));
            mnt = max(mnt, max(max(fkey(-a.x), fkey(-a.y)), max(fkey(-a.z), fkey(-a.w))));
            ms  = max(ms,  max(max(fkey(b.x),  fkey(b.y)),  max(fkey(b.z),  fkey(b.w))));
            mns = max(mns, max(max(fkey(-b.x), fkey(-b.y)), max(fkey(-b.z), fkey(-b.w))));
        }
        #pragma unroll
        for (int off = 32; off; off >>= 1){
            mt  = max(mt,  __shfl_down(mt,  off));
            mnt = max(mnt, __shfl_down(mnt, off));
            ms  = max(ms,  __shfl_down(ms,  off));
            mns = max(mns, __shfl_down(mns, off));
        }
        if (lane == 0){
            kred[warp][0] = mt; kred[warp][1] = mnt;
            kred[warp][2] = ms; kred[warp][3] = mns;
        }
        __syncthreads();
        if (tid == 0){
            unsigned q0=0u,q1=0u,q2=0u,q3=0u;
            #pragma unroll
            for (int j = 0; j < WPB; ++j){
                q0 = max(q0, kred[j][0]); q1 = max(q1, kred[j][1]);
                q2 = max(q2, kred[j][2]); q3 = max(q3, kred[j][3]);
            }
            __hip_atomic_store(&kblk[linear*4+0], q0, __ATOMIC_RELAXED, __HIP_MEMORY_SCOPE_AGENT);
            __hip_atomic_store(&kblk[linear*4+1], q1, __ATOMIC_RELAXED, __HIP_MEMORY_SCOPE_AGENT);
            __hip_atomic_store(&kblk[linear*4+2], q2, __ATOMIC_RELAXED, __HIP_MEMORY_SCOPE_AGENT);
            __hip_atomic_store(&kblk[linear*4+3], q3, __ATOMIC_RELAXED, __HIP_MEMORY_SCOPE_AGENT);
        }
    }
    grid.sync();

    // ---------------- phase B: histogram GEMM ----------------
    // reduce the 256 per-block key quads (L2-hit)
    {
        unsigned m0=0u, m1=0u, m2=0u, m3=0u;
        if (tid < NBLK){
            m0 = __hip_atomic_load(&kblk[tid*4+0], __ATOMIC_RELAXED, __HIP_MEMORY_SCOPE_AGENT);
            m1 = __hip_atomic_load(&kblk[tid*4+1], __ATOMIC_RELAXED, __HIP_MEMORY_SCOPE_AGENT);
            m2 = __hip_atomic_load(&kblk[tid*4+2], __ATOMIC_RELAXED, __HIP_MEMORY_SCOPE_AGENT);
            m3 = __hip_atomic_load(&kblk[tid*4+3], __ATOMIC_RELAXED, __HIP_MEMORY_SCOPE_AGENT);
        }
        #pragma unroll
        for (int off = 32; off; off >>= 1){
            m0 = max(m0, __shfl_down(m0, off));
            m1 = max(m1, __shfl_down(m1, off));
            m2 = max(m2, __shfl_down(m2, off));
            m3 = max(m3, __shfl_down(m3, off));
        }
        if (lane == 0){
            kred[warp][0] = m0; kred[warp][1] = m1;
            kred[warp][2] = m2; kred[warp][3] = m3;
        }
        __syncthreads();
    }
    unsigned k0=0u,k1=0u,k2=0u,k3=0u;
    #pragma unroll
    for (int j = 0; j < WPB; ++j){
        k0 = max(k0, kred[j][0]); k1 = max(k1, kred[j][1]);
        k2 = max(k2, kred[j][2]); k3 = max(k3, kred[j][3]);
    }
    float tmax =  fdecode(k0), tmin = -fdecode(k1);
    float smax =  fdecode(k2), smin = -fdecode(k3);
    float tsc = 64.f / (tmax - tmin);
    float ssc = 64.f / (smax - smin);

    char* As = (char*)smem4 + warp*WAVE_B; // this wave's tiles
    char* Bs = As + TILE_B;

    // clear this wave's tiles (wave-private: no barrier needed)
    {
        int4* wz = (int4*)As;
        int4 z4 = {0,0,0,0};
        #pragma unroll
        for (int i = 0; i < 11; ++i){
            int idx = i*64 + lane;
            if (idx < WAVE_B/16) wz[idx] = z4;
        }
    }

    const float* tb = t + (size_t)by*BATCH_N;
    const float* sb = s + (size_t)by*BATCH_N;

    v4i acc[4][4];
    #pragma unroll
    for (int i = 0; i < 4; ++i)
        #pragma unroll
        for (int j = 0; j < 4; ++j)
            acc[i][j] = (v4i){0,0,0,0};

    int c0 = bx*WPB + warp;                // wave slot within batch [0, 1536)
    // depth-2 prefetch pipeline
    float tq0 = tb[(size_t)c0*64 + lane];
    float sq0 = sb[(size_t)c0*64 + lane];
    float tq1 = tb[(size_t)(c0 + GWAVES)*64 + lane];
    float sq1 = sb[(size_t)(c0 + GWAVES)*64 + lane];

    for (int it = 0; it < NCHUNK; ++it){
        // issue prefetch for chunk it+2 (clamped to a safe in-range address)
        int cpre = c0 + (it < NCHUNK-2 ? (it + 2)*GWAVES : 0);
        float tnn = tb[(size_t)cpre*64 + lane];
        float snn = sb[(size_t)cpre*64 + lane];

        float vt = (tq0 - tmin) * tsc;     // in [0,64]
        float vs = (sq0 - smin) * ssc;
        int it0 = (int)floorf(vt);         // 0..64
        int is0 = (int)floorf(vs);
        float wt[4], wsv[4];
        bw4(vt - (float)it0, wt);
        bw4(vs - (float)is0, wsv);

        // quantized scatter: lane owns voxel column `lane`; padded rows it0..it0+3
        // (bin it0-1..it0+2 shifted +1), unconditional — pad rows are never read.
        char* pa = As + it0*ROWB + lane;
        char* pb = Bs + is0*ROWB + lane;
        #pragma unroll
        for (int k = 0; k < 4; ++k){
            pa[k*ROWB] = (char)__float2int_rn(wt[k]  * QS);
            pb[k*ROWB] = (char)__float2int_rn(wsv[k] * QS);
        }

        // fragments + MFMA (same-wave DS ops complete in order)
        v4i af[4], bf[4];
        #pragma unroll
        for (int m = 0; m < 4; ++m)
            af[m] = *(const v4i*)(As + (m*16 + rrow + 1)*ROWB + kgrp*16);
        #pragma unroll
        for (int n = 0; n < 4; ++n)
            bf[n] = *(const v4i*)(Bs + (n*16 + rrow + 1)*ROWB + kgrp*16);
        #pragma unroll
        for (int m = 0; m < 4; ++m)
            #pragma unroll
            for (int n = 0; n < 4; ++n)
                acc[m][n] = __builtin_amdgcn_mfma_i32_16x16x64_i8(af[m], bf[n], acc[m][n], 0, 0, 0);

        // zero-restore the scattered entries
        __asm__ volatile("" ::: "memory");
        #pragma unroll
        for (int k = 0; k < 4; ++k){
            pa[k*ROWB] = 0;
            pb[k*ROWB] = 0;
        }

        tq0 = tq1; sq0 = sq1;
        tq1 = tnn; sq1 = snn;
    }

    // merge: reuse tile LDS (dead) as f32 staging. Pair p = warp>>1 uses region
    // at smem + p*2*WAVE_B (6 regions x 16884 B <= 130560 B). Even warp stores,
    // odd warp adds; then cooperative sum of 6 regions -> global atomics.
    const float dq = 1.f / (QS*QS);
    float* fmw = (float*)((char*)smem4 + (warp >> 1)*(2*WAVE_B));
    __syncthreads();                       // all waves done with their tiles
    if ((warp & 1) == 0){
        #pragma unroll
        for (int m = 0; m < 4; ++m)
            #pragma unroll
            for (int n = 0; n < 4; ++n)
                #pragma unroll
                for (int r = 0; r < 4; ++r)
                    fmw[(m*16 + kgrp*4 + r)*MROW + n*16 + rrow] = (float)acc[m][n][r] * dq;
    }
    __syncthreads();
    if ((warp & 1) == 1){
        #pragma unroll
        for (int m = 0; m < 4; ++m)
            #pragma unroll
            for (int n = 0; n < 4; ++n)
                #pragma unroll
                for (int r = 0; r < 4; ++r)
                    fmw[(m*16 + kgrp*4 + r)*MROW + n*16 + rrow] += (float)acc[m][n][r] * dq;
    }
    __syncthreads();
    {
        float* g = ghist + by*4096;
        for (int idx = tid; idx < 4096; idx += THREADS){
            int l = (idx >> 6)*MROW + (idx & 63);
            float v = 0.f;
            #pragma unroll
            for (int p = 0; p < 6; ++p)
                v += *((const float*)((const char*)smem4 + p*(2*WAVE_B)) + l);
            unsafeAtomicAdd(&g[idx], v);
        }
    }
    grid.sync();

    // ---------------- phase C: block 0 computes the NMI loss ----------------
    if (linear != 0) return;
    float* sh = (float*)smem4;             // 32768 B, tiles dead
    for (int i = tid; i < 8192; i += THREADS)
        sh[i] = __hip_atomic_load(&ghist[i], __ATOMIC_RELAXED, __HIP_MEMORY_SCOPE_AGENT);
    __syncthreads();

    float loc = 0.f;
    for (int i = tid; i < 8192; i += THREADS) loc += sh[i];
    float total = bsum(loc, redf);
    float inv = 1.f / total;

    float nmi[2];
    for (int b = 0; b < 2; ++b){
        const float* h = sh + b*4096;
        float lj = 0.f;
        for (int i = tid; i < 4096; i += THREADS){
            float p = h[i]*inv;
            lj += p*logf(p + 1e-12f);
        }
        float Hj = -bsum(lj, redf);
        float lt = 0.f;
        if (tid < 64){
            float r = 0.f;
            for (int j = 0; j < 64; ++j) r += h[tid*64 + j];
            float p = r*inv;
            lt = p*logf(p + 1e-12f);
        }
        float Ht = -bsum(lt, redf);
        float ls = 0.f;
        if (tid < 64){
            float c = 0.f;
            for (int j = 0; j < 64; ++j) c += h[j*64 + tid];
            float p = c*inv;
            ls = p*logf(p + 1e-12f);
        }
        float Hs = -bsum(ls, redf);
        nmi[b] = (Ht + Hs) / Hj;
    }
    if (tid == 0) out[0] = -0.5f*(nmi[0] + nmi[1]);
}

extern "C" void kernel_launch(void* const* d_in, const int* in_sizes, int n_in,
                              void* d_out, int out_size, void* d_ws, size_t ws_size,
                              hipStream_t stream) {
    const float* t = (const float*)d_in[0];
    const float* s = (const float*)d_in[1];
    float* outp = (float*)d_out;
    float* ghist = (float*)((char*)d_ws + OFF_GHIST);
    unsigned* kblk = (unsigned*)((char*)d_ws + OFF_KBLK);

    void* args[] = {(void*)&t, (void*)&s, (void*)&ghist, (void*)&kblk, (void*)&outp};
    hipLaunchCooperativeKernel((void*)k_nmi, dim3(GBX, 2), dim3(THREADS),
                               args, 0, stream);
}

// Round 6
// 103.443 us; speedup vs baseline: 1.3959x; 1.3959x over previous
//
#include <hip/hip_runtime.h>
#include <math.h>

#define BATCH_N 884736    // 96*96*96
#define NTOT   1769472    // 2*BATCH_N
#define ROWB  80          // tile row stride bytes (64 voxels + 16 pad, 16B aligned)
#define TILE_B 5440       // 68*80 bytes per tile (rows -1..66 padded)
#define WAVE_B 10880      // A+B tiles per wave
#define MROW 66           // merge region row stride (floats)
#define QS 190.0f         // weight quantization scale (max w=2/3 -> 127)
#define WPB 6             // waves per k_gemm block
#define THREADS 384
#define GBX 256           // k_gemm blocks per batch -> 512 total = exactly 2/CU
#define GWAVES 1536       // waves per batch: 13824/1536 = exactly 9 chunks/wave
#define NCHUNK 9
#define KBLK 512          // k_minmax blocks

// ws layout (bytes):
//   ghist  at   256 : float[2][4096]   (zeroed by k_minmax; atomic-accumulated by k_gemm)
//   kblk   at 36864 : uint4[512]       (plain-stored by k_minmax)
#define OFF_GHIST 256
#define OFF_KBLK 36864

typedef int  v4i __attribute__((ext_vector_type(4)));

// monotone float->uint key: max over keys == max over floats
__device__ __forceinline__ unsigned fkey(float x){
    unsigned u = __float_as_uint(x);
    return (u & 0x80000000u) ? ~u : (u | 0x80000000u);
}
__device__ __forceinline__ float fdecode(unsigned k){
    return __uint_as_float((k & 0x80000000u) ? (k ^ 0x80000000u) : ~k);
}

// cubic B-spline weights for the 4 bins it0-1..it0+2, u = frac(vt) in [0,1)
__device__ __forceinline__ void bw4(float u, float w[4]){
    float um = 1.f - u;
    float u2 = u*u, um2 = um*um;
    w[0] = um2*um*(1.f/6.f);
    w[3] = u2*u*(1.f/6.f);
    w[1] = 0.6666666666666667f - u2 + 0.5f*u2*u;
    w[2] = 0.6666666666666667f - um2 + 0.5f*um2*um;
}

// per-block min/max -> plain store into kblk[block]; blocks 0..7 also zero ghist
__global__ void __launch_bounds__(256)
k_minmax(const float4* __restrict__ t4, const float4* __restrict__ s4,
         int n4, uint4* __restrict__ kblk, float* __restrict__ ghist){
    __shared__ unsigned red[4][4];   // [wave][key]

    if (blockIdx.x < 8){
        ghist[blockIdx.x*1024 + threadIdx.x] = 0.f;
        ghist[blockIdx.x*1024 + 256 + threadIdx.x] = 0.f;
        ghist[blockIdx.x*1024 + 512 + threadIdx.x] = 0.f;
        ghist[blockIdx.x*1024 + 768 + threadIdx.x] = 0.f;
    }

    unsigned mt=0u, mnt=0u, ms=0u, mns=0u;
    int stride = gridDim.x * blockDim.x;
    for (int i = blockIdx.x*blockDim.x + threadIdx.x; i < n4; i += stride){
        float4 a = t4[i];
        float4 b = s4[i];
        mt  = max(mt,  max(max(fkey(a.x),  fkey(a.y)),  max(fkey(a.z),  fkey(a.w))));
        mnt = max(mnt, max(max(fkey(-a.x), fkey(-a.y)), max(fkey(-a.z), fkey(-a.w))));
        ms  = max(ms,  max(max(fkey(b.x),  fkey(b.y)),  max(fkey(b.z),  fkey(b.w))));
        mns = max(mns, max(max(fkey(-b.x), fkey(-b.y)), max(fkey(-b.z), fkey(-b.w))));
    }
    #pragma unroll
    for (int off = 32; off; off >>= 1){
        mt  = max(mt,  __shfl_down(mt,  off));
        mnt = max(mnt, __shfl_down(mnt, off));
        ms  = max(ms,  __shfl_down(ms,  off));
        mns = max(mns, __shfl_down(mns, off));
    }
    int wid = threadIdx.x >> 6;
    if ((threadIdx.x & 63) == 0){
        red[wid][0] = mt; red[wid][1] = mnt; red[wid][2] = ms; red[wid][3] = mns;
    }
    __syncthreads();
    if (threadIdx.x == 0){
        uint4 q;
        q.x = max(max(red[0][0], red[1][0]), max(red[2][0], red[3][0]));
        q.y = max(max(red[0][1], red[1][1]), max(red[2][1], red[3][1]));
        q.z = max(max(red[0][2], red[1][2]), max(red[2][2], red[3][2]));
        q.w = max(max(red[0][3], red[1][3]), max(red[2][3], red[3][3]));
        kblk[blockIdx.x] = q;
    }
}

// joint histogram as tall-skinny GEMM on int8 (wave-private LDS tiles, i8 MFMA).
// R3-proven core. 6 waves/block, 512 blocks total = exactly 2 blocks/CU
// (12 waves/CU), exactly 9 chunks/wave — balanced, latency-chain minimized.
// Epilogue: 3-pair LDS merge then global f32 atomic add into ghist.
__global__ void __launch_bounds__(THREADS, 3)
k_gemm(const float* __restrict__ t, const float* __restrict__ s,
       const uint4* __restrict__ kblk, float* __restrict__ ghist){
    __shared__ int4 smem4[WPB*WAVE_B/16];  // 65280 B = 6 waves * (A+B i8 tiles)
    __shared__ unsigned kred[WPB][4];

    int tid = threadIdx.x;
    int lane = tid & 63;
    int warp = tid >> 6;
    int rrow = lane & 15;                  // fragment row/col within 16-tile
    int kgrp = lane >> 4;                  // k-group (16 bytes each for K=64 i8)
    int b = blockIdx.y;

    char* As = (char*)smem4 + warp*WAVE_B; // this wave's tiles
    char* Bs = As + TILE_B;

    // initial clear of this wave's tiles (wave-private: no barrier needed)
    {
        int4* wz = (int4*)As;
        int4 z4 = {0,0,0,0};
        #pragma unroll
        for (int i = 0; i < 11; ++i){
            int idx = i*64 + lane;
            if (idx < WAVE_B/16) wz[idx] = z4;
        }
    }

    // reduce the 512 per-block key quads (redundant per block; ~L2-hit)
    {
        unsigned m0=0u, m1=0u, m2=0u, m3=0u;
        for (int i = tid; i < KBLK; i += THREADS){
            uint4 q = kblk[i];
            m0 = max(m0, q.x); m1 = max(m1, q.y);
            m2 = max(m2, q.z); m3 = max(m3, q.w);
        }
        #pragma unroll
        for (int off = 32; off; off >>= 1){
            m0 = max(m0, __shfl_down(m0, off));
            m1 = max(m1, __shfl_down(m1, off));
            m2 = max(m2, __shfl_down(m2, off));
            m3 = max(m3, __shfl_down(m3, off));
        }
        if (lane == 0){
            kred[warp][0] = m0; kred[warp][1] = m1;
            kred[warp][2] = m2; kred[warp][3] = m3;
        }
        __syncthreads();
    }
    unsigned k0=0u,k1=0u,k2=0u,k3=0u;
    #pragma unroll
    for (int j = 0; j < WPB; ++j){
        k0 = max(k0, kred[j][0]); k1 = max(k1, kred[j][1]);
        k2 = max(k2, kred[j][2]); k3 = max(k3, kred[j][3]);
    }
    float tmax =  fdecode(k0), tmin = -fdecode(k1);
    float smax =  fdecode(k2), smin = -fdecode(k3);
    float tsc = 64.f / (tmax - tmin);
    float ssc = 64.f / (smax - smin);

    const float* tb = t + (size_t)b*BATCH_N;
    const float* sb = s + (size_t)b*BATCH_N;

    v4i acc[4][4];
    #pragma unroll
    for (int i = 0; i < 4; ++i)
        #pragma unroll
        for (int j = 0; j < 4; ++j)
            acc[i][j] = (v4i){0,0,0,0};

    int c0 = blockIdx.x*WPB + warp;        // wave slot within batch [0, 1536)
    // depth-2 prefetch pipeline
    float tq0 = tb[(size_t)c0*64 + lane];
    float sq0 = sb[(size_t)c0*64 + lane];
    float tq1 = tb[(size_t)(c0 + GWAVES)*64 + lane];
    float sq1 = sb[(size_t)(c0 + GWAVES)*64 + lane];

    for (int it = 0; it < NCHUNK; ++it){
        // issue prefetch for chunk it+2 (clamped to a safe in-range address)
        int cpre = c0 + (it < NCHUNK-2 ? (it + 2)*GWAVES : 0);
        float tnn = tb[(size_t)cpre*64 + lane];
        float snn = sb[(size_t)cpre*64 + lane];

        float vt = (tq0 - tmin) * tsc;     // in [0,64]
        float vs = (sq0 - smin) * ssc;
        int it0 = (int)floorf(vt);         // 0..64
        int is0 = (int)floorf(vs);
        float wt[4], wsv[4];
        bw4(vt - (float)it0, wt);
        bw4(vs - (float)is0, wsv);

        // quantized scatter: lane owns voxel column `lane`; padded rows it0..it0+3
        // (bin it0-1..it0+2 shifted +1), unconditional — pad rows are never read.
        char* pa = As + it0*ROWB + lane;
        char* pb = Bs + is0*ROWB + lane;
        #pragma unroll
        for (int k = 0; k < 4; ++k){
            pa[k*ROWB] = (char)__float2int_rn(wt[k]  * QS);
            pb[k*ROWB] = (char)__float2int_rn(wsv[k] * QS);
        }

        // fragments + MFMA (same-wave DS ops complete in order)
        v4i af[4], bf[4];
        #pragma unroll
        for (int m = 0; m < 4; ++m)
            af[m] = *(const v4i*)(As + (m*16 + rrow + 1)*ROWB + kgrp*16);
        #pragma unroll
        for (int n = 0; n < 4; ++n)
            bf[n] = *(const v4i*)(Bs + (n*16 + rrow + 1)*ROWB + kgrp*16);
        #pragma unroll
        for (int m = 0; m < 4; ++m)
            #pragma unroll
            for (int n = 0; n < 4; ++n)
                acc[m][n] = __builtin_amdgcn_mfma_i32_16x16x64_i8(af[m], bf[n], acc[m][n], 0, 0, 0);

        // zero-restore the scattered entries
        __asm__ volatile("" ::: "memory");
        #pragma unroll
        for (int k = 0; k < 4; ++k){
            pa[k*ROWB] = 0;
            pb[k*ROWB] = 0;
        }

        tq0 = tq1; sq0 = sq1;
        tq1 = tnn; sq1 = snn;
    }

    // merge: reuse tile LDS (dead now) as f32 staging. Pair p = warp>>1 uses
    // region at smem + p*2*WAVE_B (3 regions x 16896 B, strides 21760 B).
    // Even warp of the pair stores, odd warp adds; then cooperative sum of the
    // 3 regions -> global f32 atomics into ghist (no partials, no reduce kernel).
    const float dq = 1.f / (QS*QS);
    float* fmw = (float*)((char*)smem4 + (warp >> 1)*(2*WAVE_B));
    __syncthreads();                       // all waves done reading their tiles
    if ((warp & 1) == 0){
        #pragma unroll
        for (int m = 0; m < 4; ++m)
            #pragma unroll
            for (int n = 0; n < 4; ++n)
                #pragma unroll
                for (int r = 0; r < 4; ++r)
                    fmw[(m*16 + kgrp*4 + r)*MROW + n*16 + rrow] = (float)acc[m][n][r] * dq;
    }
    __syncthreads();
    if ((warp & 1) == 1){
        #pragma unroll
        for (int m = 0; m < 4; ++m)
            #pragma unroll
            for (int n = 0; n < 4; ++n)
                #pragma unroll
                for (int r = 0; r < 4; ++r)
                    fmw[(m*16 + kgrp*4 + r)*MROW + n*16 + rrow] += (float)acc[m][n][r] * dq;
    }
    __syncthreads();
    {
        const float* fm0 = (const float*)smem4;
        const float* fm1 = (const float*)((char*)smem4 + 2*WAVE_B);
        const float* fm2 = (const float*)((char*)smem4 + 4*WAVE_B);
        float* g = ghist + b*4096;
        for (int idx = tid; idx < 4096; idx += THREADS){
            int l = (idx >> 6)*MROW + (idx & 63);
            unsafeAtomicAdd(&g[idx], fm0[l] + fm1[l] + fm2[l]);
        }
    }
}

__device__ __forceinline__ float blockReduceSum(float v, float* red){
    #pragma unroll
    for (int off = 32; off; off >>= 1) v += __shfl_down(v, off);
    int wid = threadIdx.x >> 6, lane = threadIdx.x & 63;
    __syncthreads();              // protect red[] from previous round
    if (lane == 0) red[wid] = v;
    __syncthreads();
    return red[0] + red[1] + red[2] + red[3];
}

__global__ void k_final(const float* __restrict__ hist, float* __restrict__ out){
    __shared__ float sh[2*4096];
    __shared__ float red[4];
    int tid = threadIdx.x;
    for (int i = tid; i < 8192; i += 256) sh[i] = hist[i];
    __syncthreads();

    float loc = 0.f;
    for (int i = tid; i < 8192; i += 256) loc += sh[i];
    float total = blockReduceSum(loc, red);
    float inv = 1.f / total;

    float nmi[2];
    for (int b = 0; b < 2; ++b){
        const float* h = sh + b*4096;
        float lj = 0.f;
        for (int i = tid; i < 4096; i += 256){
            float p = h[i]*inv;
            lj += p*logf(p + 1e-12f);
        }
        float Hj = -blockReduceSum(lj, red);
        float lt = 0.f;
        if (tid < 64){
            float r = 0.f;
            for (int j = 0; j < 64; ++j) r += h[tid*64 + j];
            float p = r*inv;
            lt = p*logf(p + 1e-12f);
        }
        float Ht = -blockReduceSum(lt, red);
        float ls = 0.f;
        if (tid < 64){
            float c = 0.f;
            for (int j = 0; j < 64; ++j) c += h[j*64 + tid];
            float p = c*inv;
            ls = p*logf(p + 1e-12f);
        }
        float Hs = -blockReduceSum(ls, red);
        nmi[b] = (Ht + Hs) / Hj;
    }
    if (tid == 0) out[0] = -0.5f*(nmi[0] + nmi[1]);
}

extern "C" void kernel_launch(void* const* d_in, const int* in_sizes, int n_in,
                              void* d_out, int out_size, void* d_ws, size_t ws_size,
                              hipStream_t stream) {
    const float* t = (const float*)d_in[0];
    const float* s = (const float*)d_in[1];
    float* out = (float*)d_out;
    float* ghist = (float*)((char*)d_ws + OFF_GHIST);
    uint4* kblk  = (uint4*)((char*)d_ws + OFF_KBLK);

    // no memset node: kblk plain-stored + ghist zeroed by k_minmax; k_gemm
    // atomically accumulates ghist. Kernel boundaries provide visibility.
    k_minmax<<<KBLK, 256, 0, stream>>>((const float4*)t, (const float4*)s, NTOT/4, kblk, ghist);
    k_gemm<<<dim3(GBX, 2), THREADS, 0, stream>>>(t, s, kblk, ghist);
    k_final<<<1, 256, 0, stream>>>(ghist, out);
}